// Round 11
// baseline (300.492 us; speedup 1.0000x reference)
//
#include <hip/hip_runtime.h>
#include <stdint.h>

typedef __attribute__((ext_vector_type(8))) short short8;
typedef __attribute__((ext_vector_type(4))) float f32x4;

#define NEG_INF (-__builtin_inff())

// Problem constants
#define B_ROWS 2048
#define N_KEYS 65536
#define DIM    128
#define NCHUNK 2048   // 32 keys per chunk

// ws layout (fast path):
//   xi:    32768 short8 = 512 KB  (x, bf16 fragment image)
//   cmaxT: 2048 chunks * 2048 rows * 4B = 16 MB  ([chunk][row], 64B-clean stores)

__device__ __forceinline__ unsigned short f2bf(float f) {
  unsigned u = __float_as_uint(f);
  u = (u + 0x7FFFu + ((u >> 16) & 1u)) >> 16;  // RNE
  return (unsigned short)u;
}

// Fragment image (16B chunks), linear in 16-row blocks:
//   chunk_idx = (row>>4)*256 + (k/8)*16 + (row&15)
// Lane-l read at (rowblk*256 + kk*64 + l) yields the MFMA 16x16x32 operand
// fragment: index = l&15, k = kk*32 + (l>>4)*8 + e.   [HW-verified r2-r9]
// C layout: col = lane&15, row = (lane>>4)*4 + reg.   [HW-verified r2-r9]

// x f32 -> xi bf16 fragment image. Thread per DST chunk (coalesced writes).
__global__ __launch_bounds__(256) void convert_x_kernel(
    const float* __restrict__ x, short8* __restrict__ xi) {
  int t = blockIdx.x * 256 + threadIdx.x;      // 32768 chunks
  int rb = t >> 8, loc = t & 255;
  int row = rb * 16 + (loc & 15);
  int c = loc >> 4;
  const float* src = x + (size_t)row * DIM + c * 8;
  f32x4 v0 = *(const f32x4*)(src);
  f32x4 v1 = *(const f32x4*)(src + 4);
  short8 o;
  o[0] = (short)f2bf(v0[0]); o[1] = (short)f2bf(v0[1]);
  o[2] = (short)f2bf(v0[2]); o[3] = (short)f2bf(v0[3]);
  o[4] = (short)f2bf(v1[0]); o[5] = (short)f2bf(v1[1]);
  o[6] = (short)f2bf(v1[2]); o[7] = (short)f2bf(v1[3]);
  xi[t] = o;
}

// Fused convert+sim: one block per 128-key tile (grid 512, 2 blocks/CU).
// Block stages+converts+masks its keys f32->bf16 LDS image ONCE (keys cross
// HBM exactly once; no global key image). Each wave lifts 32 keys into
// registers, then a barrier-free 128-iter loop over all 2048 x-rows.
// Output rows = KEYS (swapped operands) -> key-reduction in-register + 2 shfl.
// Stores cmaxT[chunk][row]: 16 consecutive floats per wave-iter = 64B line.
__global__ __launch_bounds__(256, 2) void sim6_kernel(
    const short8* __restrict__ xi, const float* __restrict__ keys,
    const int* __restrict__ act, float* __restrict__ cmaxT) {
  __shared__ short8 Bs[2048];   // 32 KB: 128-key bf16 fragment image
  const int tid = threadIdx.x;
  const int w = tid >> 6, l = tid & 63;
  const int tile = blockIdx.x;  // 128-key tile

  // Stage + convert + mask keys (dst-linear ds_write, conflict-free).
  const float* kb = keys + (size_t)tile * (128 * DIM);
#pragma unroll
  for (int it = 0; it < 8; ++it) {
    int li = it * 256 + tid;
    int rl = ((li >> 8) << 4) + (li & 15);
    int c = (li >> 4) & 15;
    const float* src = kb + rl * DIM + c * 8;
    f32x4 v0 = *(const f32x4*)(src);
    f32x4 v1 = *(const f32x4*)(src + 4);
    int a = act[tile * 128 + rl];
    short8 o;
    o[0] = (short)f2bf(v0[0]); o[1] = (short)f2bf(v0[1]);
    o[2] = (short)f2bf(v0[2]); o[3] = (short)f2bf(v0[3]);
    o[4] = (short)f2bf(v1[0]); o[5] = (short)f2bf(v1[1]);
    o[6] = (short)f2bf(v1[2]); o[7] = (short)f2bf(v1[3]);
    if (!a) o = short8{0, 0, 0, 0, 0, 0, 0, 0};
    Bs[li] = o;
  }
  __syncthreads();

  // Lift this wave's 32 keys (2 x 16-key fragments x 4 k-steps) = 32 VGPR.
  short8 kf[2][4];  // [mi][kk]
#pragma unroll
  for (int mi = 0; mi < 2; mi++) {
    int kb2 = w * 2 + mi;       // 16-key block within tile
#pragma unroll
    for (int kk = 0; kk < 4; kk++)
      kf[mi][kk] = Bs[kb2 * 256 + kk * 64 + l];
  }
  // Pin kf in registers: ds_reads cannot sink past a potential memory writer.
  asm volatile("" ::: "memory");

  const int chunk = tile * 4 + w;   // 32-key chunk id
  float* cbase = cmaxT + (size_t)chunk * B_ROWS;

  // Barrier-free main loop: 128 iters x 16 x-rows.
  for (int it = 0; it < 128; ++it) {
    short8 xf[4];
#pragma unroll
    for (int kk = 0; kk < 4; kk++)
      xf[kk] = xi[it * 256 + kk * 64 + l];

    f32x4 acc[2];
#pragma unroll
    for (int mi = 0; mi < 2; mi++) acc[mi] = f32x4{0.f, 0.f, 0.f, 0.f};

#pragma unroll
    for (int kk = 0; kk < 4; kk++)
#pragma unroll
      for (int mi = 0; mi < 2; mi++)
        acc[mi] = __builtin_amdgcn_mfma_f32_16x16x32_bf16(
            kf[mi][kk], xf[kk], acc[mi], 0, 0, 0);

    // Per-x-row max over this wave's 32 keys:
    // key = (w*2+mi)*16 + (l>>4)*4 + r ; xrow = it*16 + (l&15).
    float v = acc[0][0];
#pragma unroll
    for (int mi = 0; mi < 2; mi++)
#pragma unroll
      for (int r = 0; r < 4; r++) v = fmaxf(v, acc[mi][r]);
    v = fmaxf(v, __shfl_xor(v, 16));
    v = fmaxf(v, __shfl_xor(v, 32));
    if (l < 16) cbase[it * 16 + l] = v;   // 64B contiguous per wave-iter
  }
}

// 16 rows per block (grid 128): read cmaxT[chunk][row] in 64B-coalesced
// segments (each line once), per-row max + threshold, fp64-rescore candidate
// 32-key chunks with all 256 threads (8 thr/key x 16 dims, deterministic
// butterfly), exact argmax w/ first-index tie-break, write outputs.
// Margin 0.75 >> 2x bf16 one-sided bound ~0.55.
__global__ __launch_bounds__(256) void finalize4_kernel(
    const float* __restrict__ x, const float* __restrict__ keys,
    const float* __restrict__ vals, const int* __restrict__ act,
    const float* __restrict__ cmaxT, float* __restrict__ out) {
  __shared__ float xr[16][128];      // 8 KB
  __shared__ float wmax[4][16];
  __shared__ float thr_s[16];
  __shared__ int pr_chunk[128];
  __shared__ int pr_row[128];
  __shared__ int npair;
  __shared__ double ps[32];
  __shared__ double best_v[16];
  __shared__ int best_n[16];
  const int tid = threadIdx.x;
  const int w = tid >> 6, l = tid & 63;
  const int r0 = blockIdx.x * 16;
  const int my_row = tid & 15;       // row within the 16-row slab
  const int ci0 = tid >> 4;          // chunk phase 0..15

#pragma unroll
  for (int i = 0; i < 8; i++) {
    int idx = tid + i * 256;
    xr[idx >> 7][idx & 127] = x[(size_t)(r0 + (idx >> 7)) * DIM + (idx & 127)];
  }
  if (tid < 16) { best_v[tid] = -(double)__builtin_inf(); best_n[tid] = 0x7FFFFFFF; }
  if (tid == 0) npair = 0;
  __syncthreads();

  // Phase 1: per-row max over 2048 chunks.
  float lm = NEG_INF;
  for (int i = 0; i < 128; i++) {
    int c = ci0 + 16 * i;
    lm = fmaxf(lm, cmaxT[(size_t)c * B_ROWS + r0 + my_row]);
  }
  lm = fmaxf(lm, __shfl_xor(lm, 16));  // fold ci0 within wave
  lm = fmaxf(lm, __shfl_xor(lm, 32));
  if (l < 16) wmax[w][l] = lm;
  __syncthreads();
  if (tid < 16)
    thr_s[tid] = fmaxf(fmaxf(wmax[0][tid], wmax[1][tid]),
                       fmaxf(wmax[2][tid], wmax[3][tid])) - 0.75f;
  __syncthreads();

  // Phase 2: collect candidate (chunk,row) pairs (L2-hot re-read).
  float thr = thr_s[my_row];
  for (int i = 0; i < 128; i++) {
    int c = ci0 + 16 * i;
    float v = cmaxT[(size_t)c * B_ROWS + r0 + my_row];
    if (v > thr) {
      int p = atomicAdd(&npair, 1);
      if (p < 128) { pr_chunk[p] = c; pr_row[p] = my_row; }
    }
  }
  __syncthreads();
  int np = npair; if (np > 128) np = 128;

  // Phase 3: fp64 rescore each pair (32 keys x 8 threads x 16 dims).
  const int key_off = tid >> 3;      // 0..31
  const int d0 = (tid & 7) * 16;
  for (int p = 0; p < np; p++) {
    int c = pr_chunk[p], row = pr_row[p];
    int n = c * 32 + key_off;
    const float* kr = keys + (size_t)n * DIM + d0;
    const float* xv = &xr[row][d0];
    double s = 0.0;
#pragma unroll
    for (int u = 0; u < 16; u += 4) {
      f32x4 kv = *(const f32x4*)(kr + u);
      s += (double)xv[u] * (double)kv[0];
      s += (double)xv[u + 1] * (double)kv[1];
      s += (double)xv[u + 2] * (double)kv[2];
      s += (double)xv[u + 3] * (double)kv[3];
    }
    s += __shfl_xor(s, 1);   // deterministic 8-lane butterfly
    s += __shfl_xor(s, 2);
    s += __shfl_xor(s, 4);
    if ((tid & 7) == 0)
      ps[key_off] = (act[n] != 0) ? s : -(double)__builtin_inf();
    __syncthreads();
    if (tid == 0) {
      for (int k = 0; k < 32; k++) {
        int n2 = c * 32 + k;
        if (ps[k] > best_v[row] || (ps[k] == best_v[row] && n2 < best_n[row])) {
          best_v[row] = ps[k]; best_n[row] = n2;
        }
      }
    }
    __syncthreads();
  }

  // Phase 4: outputs.
  if (tid < 16) {
    out[262144 + r0 + tid] = (float)best_v[tid];  // confidence
    out[264192 + r0 + tid] = (float)best_n[tid];  // best_match_idx
  }
  __syncthreads();
#pragma unroll
  for (int i = 0; i < 8; i++) {
    int idx = tid + i * 256;
    int row = idx >> 7, d = idx & 127;
    out[(size_t)(r0 + row) * DIM + d] = vals[(size_t)best_n[row] * DIM + d];
  }
}

// ---------- ws-free fallback (only if ws_size too small): exact fp64 ----------
__global__ __launch_bounds__(256) void direct_kernel(
    const float* __restrict__ x, const float* __restrict__ keys,
    const float* __restrict__ vals, const int* __restrict__ act,
    float* __restrict__ out) {
  __shared__ float xr[8][128];
  __shared__ double redv[8][4];
  __shared__ int redn[8][4];
  __shared__ int bests[8];
  const int tid = threadIdx.x;
  const int r0 = blockIdx.x * 8;
  const int w = tid >> 6, l = tid & 63;
#pragma unroll
  for (int i = 0; i < 4; i++) {
    int idx = tid + i * 256;
    xr[idx >> 7][idx & 127] = x[(size_t)(r0 + (idx >> 7)) * 128 + (idx & 127)];
  }
  __syncthreads();

  double bv[8];
  int bn[8];
#pragma unroll
  for (int r = 0; r < 8; r++) { bv[r] = -(double)__builtin_inf(); bn[r] = 0x7FFFFFFF; }

  for (int n = tid; n < N_KEYS; n += 256) {
    if (act[n] == 0) continue;
    const float* kr = keys + (size_t)n * 128;
    double s[8];
#pragma unroll
    for (int r = 0; r < 8; r++) s[r] = 0.0;
    for (int d = 0; d < 128; d += 4) {
      f32x4 kv = *(const f32x4*)(kr + d);
#pragma unroll
      for (int r = 0; r < 8; r++) {
        s[r] += (double)xr[r][d] * (double)kv[0];
        s[r] += (double)xr[r][d + 1] * (double)kv[1];
        s[r] += (double)xr[r][d + 2] * (double)kv[2];
        s[r] += (double)xr[r][d + 3] * (double)kv[3];
      }
    }
#pragma unroll
    for (int r = 0; r < 8; r++)
      if (s[r] > bv[r]) { bv[r] = s[r]; bn[r] = n; }
  }

#pragma unroll
  for (int r = 0; r < 8; r++) {
    double v = bv[r]; int n = bn[r];
#pragma unroll
    for (int s = 1; s < 64; s <<= 1) {
      double ov = __shfl_xor(v, s);
      int on = __shfl_xor(n, s);
      if (ov > v || (ov == v && on < n)) { v = ov; n = on; }
    }
    if (l == 0) { redv[r][w] = v; redn[r][w] = n; }
  }
  __syncthreads();
  if (tid < 8) {
    double v = redv[tid][0]; int n = redn[tid][0];
#pragma unroll
    for (int j = 1; j < 4; j++) {
      double ov = redv[tid][j]; int on = redn[tid][j];
      if (ov > v || (ov == v && on < n)) { v = ov; n = on; }
    }
    bests[tid] = n;
    out[262144 + r0 + tid] = (float)v;
    out[264192 + r0 + tid] = (float)n;
  }
  __syncthreads();
#pragma unroll
  for (int i = 0; i < 4; i++) {
    int idx = tid + i * 256;
    int r = idx >> 7, d = idx & 127;
    out[(size_t)(r0 + r) * 128 + d] = vals[(size_t)bests[r] * 128 + d];
  }
}

extern "C" void kernel_launch(void* const* d_in, const int* in_sizes, int n_in,
                              void* d_out, int out_size, void* d_ws, size_t ws_size,
                              hipStream_t stream) {
  const float* x    = (const float*)d_in[0];
  const float* keys = (const float*)d_in[1];
  const float* vals = (const float*)d_in[2];
  const int*   act  = (const int*)d_in[3];
  float* out = (float*)d_out;

  const size_t need = (size_t)32768 * sizeof(short8) +
                      (size_t)NCHUNK * B_ROWS * sizeof(float);
  if (ws_size >= need) {
    short8* xi    = (short8*)d_ws;
    float*  cmaxT = (float*)(xi + 32768);
    convert_x_kernel<<<128, 256, 0, stream>>>(x, xi);
    sim6_kernel<<<512, 256, 0, stream>>>(xi, keys, act, cmaxT);
    finalize4_kernel<<<128, 256, 0, stream>>>(x, keys, vals, act, cmaxT, out);
  } else {
    direct_kernel<<<256, 256, 0, stream>>>(x, keys, vals, act, out);
  }
}

// Round 12
// 171.220 us; speedup vs baseline: 1.7550x; 1.7550x over previous
//
#include <hip/hip_runtime.h>
#include <stdint.h>

typedef __attribute__((ext_vector_type(8))) short short8;
typedef __attribute__((ext_vector_type(4))) float f32x4;

#define NEG_INF (-__builtin_inff())

// Problem constants
#define B_ROWS 2048
#define N_KEYS 65536
#define DIM    128
#define NCHUNK 1024   // 64 keys per chunk

// ws layout (fast path):
//   xi:   32768 short8 = 512 KB  (x, bf16 fragment image)
//   cmax: 2048 rows * 1024 chunks * 4B = 8 MB  ([row][chunk])

__device__ __forceinline__ unsigned short f2bf(float f) {
  unsigned u = __float_as_uint(f);
  u = (u + 0x7FFFu + ((u >> 16) & 1u)) >> 16;  // RNE
  return (unsigned short)u;
}

// Fragment image (16B chunks), linear in 16-row blocks:
//   chunk_idx = (row>>4)*256 + (k/8)*16 + (row&15)
// Lane-l read at (rowblk*256 + kk*64 + l) yields the MFMA 16x16x32 operand
// fragment: index = l&15, k = kk*32 + (l>>4)*8 + e.   [HW-verified r2-r11]
// C layout: col = lane&15, row = (lane>>4)*4 + reg.   [HW-verified r2-r11]

// x f32 -> xi bf16 fragment image (x only; keys converted in-wave in sim7).
__global__ __launch_bounds__(256) void convert_x_kernel(
    const float* __restrict__ x, short8* __restrict__ xi) {
  int t = blockIdx.x * 256 + threadIdx.x;      // 32768 chunks
  int rb = t >> 8, loc = t & 255;
  int row = rb * 16 + (loc & 15);
  int c = loc >> 4;
  const float* src = x + (size_t)row * DIM + c * 8;
  f32x4 v0 = *(const f32x4*)(src);
  f32x4 v1 = *(const f32x4*)(src + 4);
  short8 o;
  o[0] = (short)f2bf(v0[0]); o[1] = (short)f2bf(v0[1]);
  o[2] = (short)f2bf(v0[2]); o[3] = (short)f2bf(v0[3]);
  o[4] = (short)f2bf(v1[0]); o[5] = (short)f2bf(v1[1]);
  o[6] = (short)f2bf(v1[2]); o[7] = (short)f2bf(v1[3]);
  xi[t] = o;
}

// Grid (256 key-tiles x 4 x-quarters) = 1024 blocks (4/CU), 4 waves/block,
// NO LDS. Wave w loads its 64 keys DIRECTLY from f32 keys (one-time, 32
// loads/lane, L3-served on re-reads), converts+masks to bf16 fragments in
// registers, then a barrier-free 32-iter loop over its 512-row x-quarter
// (16 rows/iter, xf from L1/L2-resident xi shared by the block's 4 waves).
// Output rows = KEYS (swapped operands) -> key-reduction in-register + 2 shfl.
__global__ __launch_bounds__(256, 4) void sim7_kernel(
    const short8* __restrict__ xi, const float* __restrict__ keys,
    const int* __restrict__ act, float* __restrict__ cmax) {
  const int tid = threadIdx.x;
  const int w = tid >> 6, l = tid & 63;
  const int tile = blockIdx.x;      // 256-key tile
  const int q = blockIdx.y;         // x-quarter (512 rows)
  const int lr = l & 15, lg = l >> 4;

  // Load + convert + mask this wave's 64 keys -> kf[4][4] (64 VGPR).
  // Fragment (block g, k-step kk): lane l holds key row g*16+(l&15),
  // dims kk*32 + (l>>4)*8 .. +7.
  short8 kf[4][4];  // [mi][kk]
#pragma unroll
  for (int mi = 0; mi < 4; mi++) {
    int g = tile * 16 + w * 4 + mi;   // 16-key block
    int row = g * 16 + lr;            // this lane's key row
    int a = act[row];
    const float* kr = keys + (size_t)row * DIM + lg * 8;
#pragma unroll
    for (int kk = 0; kk < 4; kk++) {
      f32x4 v0 = *(const f32x4*)(kr + kk * 32);
      f32x4 v1 = *(const f32x4*)(kr + kk * 32 + 4);
      short8 o;
      o[0] = (short)f2bf(v0[0]); o[1] = (short)f2bf(v0[1]);
      o[2] = (short)f2bf(v0[2]); o[3] = (short)f2bf(v0[3]);
      o[4] = (short)f2bf(v1[0]); o[5] = (short)f2bf(v1[1]);
      o[6] = (short)f2bf(v1[2]); o[7] = (short)f2bf(v1[3]);
      if (!a) o = short8{0, 0, 0, 0, 0, 0, 0, 0};
      kf[mi][kk] = o;
    }
  }
  // Pin kf in registers: loads cannot sink past a potential memory writer.
  asm volatile("" ::: "memory");

  const int chunk = tile * 4 + w;   // 64-key chunk id
  const short8* xq = xi + (size_t)q * 8192;   // 512 rows = 32 rowblks * 256

  for (int it = 0; it < 32; ++it) {
    short8 xf[4];
#pragma unroll
    for (int kk = 0; kk < 4; kk++)
      xf[kk] = xq[it * 256 + kk * 64 + l];

    f32x4 acc[4];
#pragma unroll
    for (int mi = 0; mi < 4; mi++) acc[mi] = f32x4{0.f, 0.f, 0.f, 0.f};

#pragma unroll
    for (int kk = 0; kk < 4; kk++)
#pragma unroll
      for (int mi = 0; mi < 4; mi++)
        acc[mi] = __builtin_amdgcn_mfma_f32_16x16x32_bf16(
            kf[mi][kk], xf[kk], acc[mi], 0, 0, 0);

    // Per-x-row max over this wave's 64 keys:
    // key = mi*16 + (l>>4)*4 + r ; xrow = q*512 + it*16 + (l&15).
    float v = acc[0][0];
#pragma unroll
    for (int mi = 0; mi < 4; mi++)
#pragma unroll
      for (int r = 0; r < 4; r++) v = fmaxf(v, acc[mi][r]);
    v = fmaxf(v, __shfl_xor(v, 16));
    v = fmaxf(v, __shfl_xor(v, 32));
    if (l < 16) {
      int row = q * 512 + it * 16 + lr;
      cmax[(size_t)row * NCHUNK + chunk] = v;
    }
  }
}

// One block per row (grid 2048, measured-good r9): reduce 1024 chunk maxima
// (coalesced), fp64-rescore candidate 64-key chunks with ALL 256 threads
// (4 thr/key x 32 dims, deterministic butterfly), exact argmax w/ first-index
// tie-break. Margin 0.75 >> 2x bf16 one-sided bound ~0.55.
__global__ __launch_bounds__(256) void finalize3_kernel(
    const float* __restrict__ x, const float* __restrict__ keys,
    const float* __restrict__ vals, const int* __restrict__ act,
    const float* __restrict__ cmax, float* __restrict__ out) {
  __shared__ float xr[128];
  __shared__ float wred[4];
  __shared__ int cand[1024];
  __shared__ int ncand;
  __shared__ double redv[4];
  __shared__ int redn[4];
  __shared__ int bestn_s;
  const int b = blockIdx.x, tid = threadIdx.x;
  const int w = tid >> 6, l = tid & 63;
  if (tid < 128) xr[tid] = x[(size_t)b * 128 + tid];
  if (tid == 0) ncand = 0;
  __syncthreads();

  const float* cm = cmax + (size_t)b * NCHUNK;
  float c[4];
  float lm = NEG_INF;
#pragma unroll
  for (int j = 0; j < 4; j++) {
    c[j] = cm[tid + j * 256];
    lm = fmaxf(lm, c[j]);
  }
#pragma unroll
  for (int s = 1; s < 64; s <<= 1) lm = fmaxf(lm, __shfl_xor(lm, s));
  if (l == 0) wred[w] = lm;
  __syncthreads();
  float M = fmaxf(fmaxf(wred[0], wred[1]), fmaxf(wred[2], wred[3]));
  float thr = M - 0.75f;

#pragma unroll
  for (int j = 0; j < 4; j++) {
    if (c[j] > thr) {
      int p = atomicAdd(&ncand, 1);
      cand[p] = tid + j * 256;
    }
  }
  __syncthreads();
  int nc = ncand;

  double bv = -(double)__builtin_inf();
  int bn = 0x7FFFFFFF;
  const int key_off = tid >> 2;        // 0..63 within chunk
  const int d0 = (tid & 3) * 32;       // 32-dim slice
  for (int ci = 0; ci < nc; ci++) {
    int n = cand[ci] * 64 + key_off;
    const float* kr = keys + (size_t)n * 128 + d0;
    double s = 0.0;
#pragma unroll
    for (int u = 0; u < 32; u += 4) {
      f32x4 kv = *(const f32x4*)(kr + u);
      s += (double)xr[d0 + u] * (double)kv[0];
      s += (double)xr[d0 + u + 1] * (double)kv[1];
      s += (double)xr[d0 + u + 2] * (double)kv[2];
      s += (double)xr[d0 + u + 3] * (double)kv[3];
    }
    // deterministic 4-lane butterfly sum (same value on all 4 lanes)
    s += __shfl_xor(s, 1);
    s += __shfl_xor(s, 2);
    if ((tid & 3) == 0 && act[n] != 0) {
      if (s > bv || (s == bv && n < bn)) { bv = s; bn = n; }
    }
  }

  // Block-wide argmax reduce (inactive lanes hold -inf).
#pragma unroll
  for (int s = 1; s < 64; s <<= 1) {
    double ov = __shfl_xor(bv, s);
    int on = __shfl_xor(bn, s);
    if (ov > bv || (ov == bv && on < bn)) { bv = ov; bn = on; }
  }
  if (l == 0) { redv[w] = bv; redn[w] = bn; }
  __syncthreads();
  if (tid == 0) {
    double v = redv[0]; int n = redn[0];
#pragma unroll
    for (int j = 1; j < 4; j++) {
      if (redv[j] > v || (redv[j] == v && redn[j] < n)) { v = redv[j]; n = redn[j]; }
    }
    bestn_s = n;
    out[262144 + b] = (float)v;        // confidence
    out[264192 + b] = (float)n;        // best_match_idx (float-encoded)
  }
  __syncthreads();
  int n = bestn_s;
  if (tid < 128) out[(size_t)b * 128 + tid] = vals[(size_t)n * 128 + tid];
}

// ---------- ws-free fallback (only if ws_size too small): exact fp64 ----------
__global__ __launch_bounds__(256) void direct_kernel(
    const float* __restrict__ x, const float* __restrict__ keys,
    const float* __restrict__ vals, const int* __restrict__ act,
    float* __restrict__ out) {
  __shared__ float xr[8][128];
  __shared__ double redv[8][4];
  __shared__ int redn[8][4];
  __shared__ int bests[8];
  const int tid = threadIdx.x;
  const int r0 = blockIdx.x * 8;
  const int w = tid >> 6, l = tid & 63;
#pragma unroll
  for (int i = 0; i < 4; i++) {
    int idx = tid + i * 256;
    xr[idx >> 7][idx & 127] = x[(size_t)(r0 + (idx >> 7)) * 128 + (idx & 127)];
  }
  __syncthreads();

  double bv[8];
  int bn[8];
#pragma unroll
  for (int r = 0; r < 8; r++) { bv[r] = -(double)__builtin_inf(); bn[r] = 0x7FFFFFFF; }

  for (int n = tid; n < N_KEYS; n += 256) {
    if (act[n] == 0) continue;
    const float* kr = keys + (size_t)n * 128;
    double s[8];
#pragma unroll
    for (int r = 0; r < 8; r++) s[r] = 0.0;
    for (int d = 0; d < 128; d += 4) {
      f32x4 kv = *(const f32x4*)(kr + d);
#pragma unroll
      for (int r = 0; r < 8; r++) {
        s[r] += (double)xr[r][d] * (double)kv[0];
        s[r] += (double)xr[r][d + 1] * (double)kv[1];
        s[r] += (double)xr[r][d + 2] * (double)kv[2];
        s[r] += (double)xr[r][d + 3] * (double)kv[3];
      }
    }
#pragma unroll
    for (int r = 0; r < 8; r++)
      if (s[r] > bv[r]) { bv[r] = s[r]; bn[r] = n; }
  }

#pragma unroll
  for (int r = 0; r < 8; r++) {
    double v = bv[r]; int n = bn[r];
#pragma unroll
    for (int s = 1; s < 64; s <<= 1) {
      double ov = __shfl_xor(v, s);
      int on = __shfl_xor(n, s);
      if (ov > v || (ov == v && on < n)) { v = ov; n = on; }
    }
    if (l == 0) { redv[r][w] = v; redn[r][w] = n; }
  }
  __syncthreads();
  if (tid < 8) {
    double v = redv[tid][0]; int n = redn[tid][0];
#pragma unroll
    for (int j = 1; j < 4; j++) {
      double ov = redv[tid][j]; int on = redn[tid][j];
      if (ov > v || (ov == v && on < n)) { v = ov; n = on; }
    }
    bests[tid] = n;
    out[262144 + r0 + tid] = (float)v;
    out[264192 + r0 + tid] = (float)n;
  }
  __syncthreads();
#pragma unroll
  for (int i = 0; i < 4; i++) {
    int idx = tid + i * 256;
    int r = idx >> 7, d = idx & 127;
    out[(size_t)(r0 + r) * 128 + d] = vals[(size_t)bests[r] * 128 + d];
  }
}

extern "C" void kernel_launch(void* const* d_in, const int* in_sizes, int n_in,
                              void* d_out, int out_size, void* d_ws, size_t ws_size,
                              hipStream_t stream) {
  const float* x    = (const float*)d_in[0];
  const float* keys = (const float*)d_in[1];
  const float* vals = (const float*)d_in[2];
  const int*   act  = (const int*)d_in[3];
  float* out = (float*)d_out;

  const size_t need = (size_t)32768 * sizeof(short8) +
                      (size_t)B_ROWS * NCHUNK * sizeof(float);
  if (ws_size >= need) {
    short8* xi   = (short8*)d_ws;
    float*  cmax = (float*)(xi + 32768);
    convert_x_kernel<<<128, 256, 0, stream>>>(x, xi);
    sim7_kernel<<<dim3(256, 4), 256, 0, stream>>>(xi, keys, act, cmax);
    finalize3_kernel<<<2048, 256, 0, stream>>>(x, keys, vals, act, cmax, out);
  } else {
    direct_kernel<<<256, 256, 0, stream>>>(x, keys, vals, act, out);
  }
}

// Round 13
// 153.664 us; speedup vs baseline: 1.9555x; 1.1143x over previous
//
#include <hip/hip_runtime.h>
#include <stdint.h>

typedef __attribute__((ext_vector_type(8))) short short8;
typedef __attribute__((ext_vector_type(4))) float f32x4;

#define NEG_INF (-__builtin_inff())

// Problem constants
#define B_ROWS 2048
#define N_KEYS 65536
#define DIM    128
#define NCHUNK 1024   // 64 keys per chunk

// ws layout (fast path):
//   xi:   32768 short8  = 512 KB  (x,    bf16 fragment image)
//   ki: 1048576 short8  = 16 MB   (keys, bf16 fragment image, MASKED: inactive=0)
//   cmax: 2048 rows * 1024 chunks * 4B = 8 MB  ([row][chunk])

__device__ __forceinline__ unsigned short f2bf(float f) {
  unsigned u = __float_as_uint(f);
  u = (u + 0x7FFFu + ((u >> 16) & 1u)) >> 16;  // RNE
  return (unsigned short)u;
}

// Fragment image (16B chunks), linear in 16-row blocks:
//   chunk_idx = (row>>4)*256 + (k/8)*16 + (row&15)
// Lane-l read at (rowblk*256 + kk*64 + l) yields the MFMA 16x16x32 operand
// fragment: index = l&15, k = kk*32 + (l>>4)*8 + e.   [HW-verified r2-r12]
// C layout: col = lane&15, row = (lane>>4)*4 + reg.   [HW-verified r2-r12]

// f32 -> bf16 fragment image for BOTH x and keys (keys masked: inactive -> 0).
// Thread per DST chunk -> coalesced writes; scattered reads L2-absorbed.
__global__ __launch_bounds__(256) void convert_kernel(
    const float* __restrict__ x, const float* __restrict__ keys,
    const int* __restrict__ act, short8* __restrict__ xi,
    short8* __restrict__ ki) {
  int t = blockIdx.x * 256 + threadIdx.x;      // 32768 + 1048576 chunks
  const float* src;
  short8* dst;
  int mask = 1;
  if (t < 32768) {
    int rb = t >> 8, loc = t & 255;
    int row = rb * 16 + (loc & 15);
    int c = loc >> 4;
    src = x + (size_t)row * DIM + c * 8;
    dst = xi + t;
  } else {
    t -= 32768;
    int rb = t >> 8, loc = t & 255;
    int row = rb * 16 + (loc & 15);
    int c = loc >> 4;
    src = keys + (size_t)row * DIM + c * 8;
    dst = ki + t;
    mask = act[row];
  }
  f32x4 v0 = *(const f32x4*)(src);
  f32x4 v1 = *(const f32x4*)(src + 4);
  short8 o;
  if (mask) {
    o[0] = (short)f2bf(v0[0]); o[1] = (short)f2bf(v0[1]);
    o[2] = (short)f2bf(v0[2]); o[3] = (short)f2bf(v0[3]);
    o[4] = (short)f2bf(v1[0]); o[5] = (short)f2bf(v1[1]);
    o[6] = (short)f2bf(v1[2]); o[7] = (short)f2bf(v1[3]);
  } else {
    o = short8{0, 0, 0, 0, 0, 0, 0, 0};
  }
  *dst = o;
}

// Grid (256 key-tiles x 4 x-quarters) = 1024 blocks (4/CU), 4 waves/block,
// NO LDS. Wave w's 64 keys come from the bf16 ki image via 16 coalesced 16B
// loads; if the allocator re-loads them in-loop, the reloads are L1-hits on a
// wave-private 4 KB region (r12 lesson: f32-direct conversion spills through
// scratch instead). Barrier-free 32-iter loop over its 512-row x-quarter.
// Output rows = KEYS (swapped operands) -> key-reduction in-register + 2 shfl.
__global__ __launch_bounds__(256, 4) void sim5_kernel(
    const short8* __restrict__ xi, const short8* __restrict__ ki,
    float* __restrict__ cmax) {
  const int tid = threadIdx.x;
  const int w = tid >> 6, l = tid & 63;
  const int tile = blockIdx.x;      // 256-key tile
  const int q = blockIdx.y;         // x-quarter (512 rows)

  // Lift this wave's 64 keys: 16 coalesced 16B loads -> 64 VGPR.
  short8 kf[4][4];  // [mi][kk]
#pragma unroll
  for (int mi = 0; mi < 4; mi++) {
    int g = tile * 16 + w * 4 + mi;           // 16-key block
#pragma unroll
    for (int kk = 0; kk < 4; kk++)
      kf[mi][kk] = ki[g * 256 + kk * 64 + l];
  }
  // Order loads before the loop (residency is the allocator's choice; the
  // reload path is L1-resident either way).
  asm volatile("" ::: "memory");

  const int chunk = tile * 4 + w;   // 64-key chunk id
  const int lr = l & 15;
  const short8* xq = xi + (size_t)q * 8192;   // 512 rows = 32 rowblks * 256

  for (int it = 0; it < 32; ++it) {
    short8 xf[4];
#pragma unroll
    for (int kk = 0; kk < 4; kk++)
      xf[kk] = xq[it * 256 + kk * 64 + l];

    f32x4 acc[4];
#pragma unroll
    for (int mi = 0; mi < 4; mi++) acc[mi] = f32x4{0.f, 0.f, 0.f, 0.f};

#pragma unroll
    for (int kk = 0; kk < 4; kk++)
#pragma unroll
      for (int mi = 0; mi < 4; mi++)
        acc[mi] = __builtin_amdgcn_mfma_f32_16x16x32_bf16(
            kf[mi][kk], xf[kk], acc[mi], 0, 0, 0);

    // Per-x-row max over this wave's 64 keys:
    // key = mi*16 + (l>>4)*4 + r ; xrow = q*512 + it*16 + (l&15).
    float v = acc[0][0];
#pragma unroll
    for (int mi = 0; mi < 4; mi++)
#pragma unroll
      for (int r = 0; r < 4; r++) v = fmaxf(v, acc[mi][r]);
    v = fmaxf(v, __shfl_xor(v, 16));
    v = fmaxf(v, __shfl_xor(v, 32));
    if (l < 16) {
      int row = q * 512 + it * 16 + lr;
      cmax[(size_t)row * NCHUNK + chunk] = v;
    }
  }
}

// One block per row: reduce 1024 chunk maxima (coalesced), fp64-rescore
// candidate 64-key chunks with ALL 256 threads (4 thr/key x 32 dims,
// deterministic butterfly-add), exact argmax w/ first-index tie-break.
// Margin 0.75 >> 2x bf16 one-sided bound ~0.55. act[] check required: an
// inactive key's TRUE score could exceed the active max.
__global__ __launch_bounds__(256) void finalize3_kernel(
    const float* __restrict__ x, const float* __restrict__ keys,
    const float* __restrict__ vals, const int* __restrict__ act,
    const float* __restrict__ cmax, float* __restrict__ out) {
  __shared__ float xr[128];
  __shared__ float wred[4];
  __shared__ int cand[1024];
  __shared__ int ncand;
  __shared__ double redv[4];
  __shared__ int redn[4];
  __shared__ int bestn_s;
  const int b = blockIdx.x, tid = threadIdx.x;
  const int w = tid >> 6, l = tid & 63;
  if (tid < 128) xr[tid] = x[(size_t)b * 128 + tid];
  if (tid == 0) ncand = 0;
  __syncthreads();

  const float* cm = cmax + (size_t)b * NCHUNK;
  float c[4];
  float lm = NEG_INF;
#pragma unroll
  for (int j = 0; j < 4; j++) {
    c[j] = cm[tid + j * 256];
    lm = fmaxf(lm, c[j]);
  }
#pragma unroll
  for (int s = 1; s < 64; s <<= 1) lm = fmaxf(lm, __shfl_xor(lm, s));
  if (l == 0) wred[w] = lm;
  __syncthreads();
  float M = fmaxf(fmaxf(wred[0], wred[1]), fmaxf(wred[2], wred[3]));
  float thr = M - 0.75f;

#pragma unroll
  for (int j = 0; j < 4; j++) {
    if (c[j] > thr) {
      int p = atomicAdd(&ncand, 1);
      cand[p] = tid + j * 256;
    }
  }
  __syncthreads();
  int nc = ncand;

  double bv = -(double)__builtin_inf();
  int bn = 0x7FFFFFFF;
  const int key_off = tid >> 2;        // 0..63 within chunk
  const int d0 = (tid & 3) * 32;       // 32-dim slice
  for (int ci = 0; ci < nc; ci++) {
    int n = cand[ci] * 64 + key_off;
    const float* kr = keys + (size_t)n * 128 + d0;
    double s = 0.0;
#pragma unroll
    for (int u = 0; u < 32; u += 4) {
      f32x4 kv = *(const f32x4*)(kr + u);
      s += (double)xr[d0 + u] * (double)kv[0];
      s += (double)xr[d0 + u + 1] * (double)kv[1];
      s += (double)xr[d0 + u + 2] * (double)kv[2];
      s += (double)xr[d0 + u + 3] * (double)kv[3];
    }
    // deterministic 4-lane butterfly sum (same value on all 4 lanes)
    s += __shfl_xor(s, 1);
    s += __shfl_xor(s, 2);
    if ((tid & 3) == 0 && act[n] != 0) {
      if (s > bv || (s == bv && n < bn)) { bv = s; bn = n; }
    }
  }

  // Block-wide argmax reduce (inactive lanes hold -inf).
#pragma unroll
  for (int s = 1; s < 64; s <<= 1) {
    double ov = __shfl_xor(bv, s);
    int on = __shfl_xor(bn, s);
    if (ov > bv || (ov == bv && on < bn)) { bv = ov; bn = on; }
  }
  if (l == 0) { redv[w] = bv; redn[w] = bn; }
  __syncthreads();
  if (tid == 0) {
    double v = redv[0]; int n = redn[0];
#pragma unroll
    for (int j = 1; j < 4; j++) {
      if (redv[j] > v || (redv[j] == v && redn[j] < n)) { v = redv[j]; n = redn[j]; }
    }
    bestn_s = n;
    out[262144 + b] = (float)v;        // confidence
    out[264192 + b] = (float)n;        // best_match_idx (float-encoded)
  }
  __syncthreads();
  int n = bestn_s;
  if (tid < 128) out[(size_t)b * 128 + tid] = vals[(size_t)n * 128 + tid];
}

// ---------- ws-free fallback (only if ws_size too small): exact fp64 ----------
__global__ __launch_bounds__(256) void direct_kernel(
    const float* __restrict__ x, const float* __restrict__ keys,
    const float* __restrict__ vals, const int* __restrict__ act,
    float* __restrict__ out) {
  __shared__ float xr[8][128];
  __shared__ double redv[8][4];
  __shared__ int redn[8][4];
  __shared__ int bests[8];
  const int tid = threadIdx.x;
  const int r0 = blockIdx.x * 8;
  const int w = tid >> 6, l = tid & 63;
#pragma unroll
  for (int i = 0; i < 4; i++) {
    int idx = tid + i * 256;
    xr[idx >> 7][idx & 127] = x[(size_t)(r0 + (idx >> 7)) * 128 + (idx & 127)];
  }
  __syncthreads();

  double bv[8];
  int bn[8];
#pragma unroll
  for (int r = 0; r < 8; r++) { bv[r] = -(double)__builtin_inf(); bn[r] = 0x7FFFFFFF; }

  for (int n = tid; n < N_KEYS; n += 256) {
    if (act[n] == 0) continue;
    const float* kr = keys + (size_t)n * 128;
    double s[8];
#pragma unroll
    for (int r = 0; r < 8; r++) s[r] = 0.0;
    for (int d = 0; d < 128; d += 4) {
      f32x4 kv = *(const f32x4*)(kr + d);
#pragma unroll
      for (int r = 0; r < 8; r++) {
        s[r] += (double)xr[r][d] * (double)kv[0];
        s[r] += (double)xr[r][d + 1] * (double)kv[1];
        s[r] += (double)xr[r][d + 2] * (double)kv[2];
        s[r] += (double)xr[r][d + 3] * (double)kv[3];
      }
    }
#pragma unroll
    for (int r = 0; r < 8; r++)
      if (s[r] > bv[r]) { bv[r] = s[r]; bn[r] = n; }
  }

#pragma unroll
  for (int r = 0; r < 8; r++) {
    double v = bv[r]; int n = bn[r];
#pragma unroll
    for (int s = 1; s < 64; s <<= 1) {
      double ov = __shfl_xor(v, s);
      int on = __shfl_xor(n, s);
      if (ov > v || (ov == v && on < n)) { v = ov; n = on; }
    }
    if (l == 0) { redv[r][w] = v; redn[r][w] = n; }
  }
  __syncthreads();
  if (tid < 8) {
    double v = redv[tid][0]; int n = redn[tid][0];
#pragma unroll
    for (int j = 1; j < 4; j++) {
      double ov = redv[tid][j]; int on = redn[tid][j];
      if (ov > v || (ov == v && on < n)) { v = ov; n = on; }
    }
    bests[tid] = n;
    out[262144 + r0 + tid] = (float)v;
    out[264192 + r0 + tid] = (float)n;
  }
  __syncthreads();
#pragma unroll
  for (int i = 0; i < 4; i++) {
    int idx = tid + i * 256;
    int r = idx >> 7, d = idx & 127;
    out[(size_t)(r0 + r) * 128 + d] = vals[(size_t)bests[r] * 128 + d];
  }
}

extern "C" void kernel_launch(void* const* d_in, const int* in_sizes, int n_in,
                              void* d_out, int out_size, void* d_ws, size_t ws_size,
                              hipStream_t stream) {
  const float* x    = (const float*)d_in[0];
  const float* keys = (const float*)d_in[1];
  const float* vals = (const float*)d_in[2];
  const int*   act  = (const int*)d_in[3];
  float* out = (float*)d_out;

  const size_t need = (size_t)(32768 + 1048576) * sizeof(short8) +
                      (size_t)B_ROWS * NCHUNK * sizeof(float);
  if (ws_size >= need) {
    short8* xi   = (short8*)d_ws;
    short8* ki   = xi + 32768;
    float*  cmax = (float*)(ki + 1048576);
    convert_kernel<<<4224, 256, 0, stream>>>(x, keys, act, xi, ki);
    sim5_kernel<<<dim3(256, 4), 256, 0, stream>>>(xi, ki, cmax);
    finalize3_kernel<<<2048, 256, 0, stream>>>(x, keys, vals, act, cmax, out);
  } else {
    direct_kernel<<<256, 256, 0, stream>>>(x, keys, vals, act, out);
  }
}